// Round 2
// baseline (11951.264 us; speedup 1.0000x reference)
//
#include <hip/hip_runtime.h>
#include <stdint.h>

// Online Neural CDE, fused persistent kernel — full fp32 datapath.
// B=128, L=64, LI=64, DATA=16, HID=128, WID=256.
// 8 groups x 32 blocks; group = 16 batches; each block holds a 1/32
// output-row-slice of every vector-field weight matrix in LDS (fp32).
// Init MLP streams its weights from global (runs once).
// Inter-block exchange of 256-wide hidden vectors via L2 (d_ws) with
// agent-scope epoch barriers.

#define NGRP 8
#define NJ   32
#define NTHR 256
#define STW  276   // dword stride for 256-col tiles (4-dword gap per 64 cols)
#define STY  132   // dword stride for 128-col y tile (gap at col 64)

// jax.nn.softplus(x) = max(x,0) + log1p(exp(-|x|))
static __device__ __forceinline__ float sp(float x) {
  return fmaxf(x, 0.f) + log1pf(expf(-fabsf(x)));
}

// np.searchsorted(kn, t, 'right') - 1, clipped to [0, 62]; 64 knots.
static __device__ __forceinline__ int seg_idx(const float* kn, float t) {
  int lo = 0, hi = 64;
  while (lo < hi) { int mid = (lo + hi) >> 1; if (kn[mid] <= t) lo = mid + 1; else hi = mid; }
  int jj = lo - 1;
  return jj < 0 ? 0 : (jj > 62 ? 62 : jj);
}

static __device__ __forceinline__ float dot4(float4 w, float4 a, float acc) {
  acc = fmaf(w.x, a.x, acc);
  acc = fmaf(w.y, a.y, acc);
  acc = fmaf(w.z, a.z, acc);
  return fmaf(w.w, a.w, acc);
}

// Group barrier: monotonic epoch target on a per-group counter (agent scope).
static __device__ __forceinline__ void gbar(uint32_t* cnt, uint32_t target) {
  __syncthreads();  // all block lanes' global writes drained (vmcnt0 at barrier)
  if (threadIdx.x == 0) {
    __builtin_amdgcn_fence(__ATOMIC_RELEASE, "agent");  // writeback L2 (covers blockmates)
    __hip_atomic_fetch_add(cnt, 1u, __ATOMIC_RELAXED, __HIP_MEMORY_SCOPE_AGENT);
    uint32_t it = 0;
    while (__hip_atomic_load(cnt, __ATOMIC_RELAXED, __HIP_MEMORY_SCOPE_AGENT) < target) {
      __builtin_amdgcn_s_sleep(1);
      if (++it > (1u << 20)) break;  // failsafe (would surface as wrong output, not hang)
    }
    __builtin_amdgcn_fence(__ATOMIC_ACQUIRE, "agent");  // invalidate before reads
  }
  __syncthreads();
}

__global__ void __launch_bounds__(NTHR)
ncde_kernel(const float* __restrict__ ts, const float* __restrict__ tsi,
            const float* __restrict__ obs, const float* __restrict__ tmax,
            const float* __restrict__ i_win, const float* __restrict__ i_bin,
            const float* __restrict__ i_wmid, const float* __restrict__ i_bmid,
            const float* __restrict__ i_wout, const float* __restrict__ i_bout,
            const float* __restrict__ v_win, const float* __restrict__ v_bin,
            const float* __restrict__ v_wmid, const float* __restrict__ v_bmid,
            const float* __restrict__ v_wout, const float* __restrict__ v_bout,
            float* __restrict__ out, uint32_t* __restrict__ ws)
{
  __shared__ __align__(16) float w_l4[64][STW];   // v_wout rows 64j..64j+63
  __shared__ __align__(16) float w_m0[8][STW];    // v_wmid[0] rows 8j..
  __shared__ __align__(16) float w_m1[8][STW];    // v_wmid[1] rows 8j..
  __shared__ __align__(16) float w_l1[8][STY];    // v_win rows 8j..
  __shared__ __align__(16) float s_act[16][STW];  // staged 256-wide activations
  __shared__ __align__(16) float s_y[16][STY];    // staged 128-wide y input
  __shared__ __align__(16) float s_ts[16][64];
  __shared__ __align__(16) float s_kn[16][64];
  __shared__ float s_dx[16][16];
  __shared__ float s_dt[16], s_tm[16];
  __shared__ float sb_l1[8], sb_m0[8], sb_m1[8], sb_l4[64];

  const int tid = threadIdx.x;
  const int bid = blockIdx.x;
  const int g = bid & 7;    // group (== XCD under round-robin dispatch; perf only)
  const int j = bid >> 3;   // slice 0..31

  uint32_t* cnt = ws + (size_t)g * 64;                       // 256B-spaced counters
  float* base = (float*)(ws + 512) + (size_t)g * 20480;
  float* yw  = base;          // [2][16][128]
  float* kw  = base + 4096;   // [16][128]
  float* h1g = base + 6144;   // [16][256]
  float* h2g = base + 10240;
  float* h3g = base + 14336;

  // ---------------- load weight slices -> LDS (fp32, gapped cols) ----------
  for (int e2 = tid; e2 < 64 * 64; e2 += NTHR) {   // w_l4: 64 rows x 64 f4
    int r = e2 >> 6, c4 = e2 & 63; int k = 4 * c4;
    float4 v = *(const float4*)(v_wout + (size_t)(64 * j + r) * 256 + k);
    *(float4*)&w_l4[r][k + 4 * (k >> 6)] = v;
  }
  for (int e2 = tid; e2 < 8 * 64; e2 += NTHR) {    // mids: 8 rows x 64 f4 each
    int r = e2 >> 6, c4 = e2 & 63; int k = 4 * c4;
    float4 a = *(const float4*)(v_wmid + (size_t)(8 * j + r) * 256 + k);
    float4 b2 = *(const float4*)(v_wmid + 65536 + (size_t)(8 * j + r) * 256 + k);
    int col = k + 4 * (k >> 6);
    *(float4*)&w_m0[r][col] = a;
    *(float4*)&w_m1[r][col] = b2;
  }
  {                                                // w_l1: 8 rows x 32 f4
    int e2 = tid; int r = e2 >> 5, c4 = e2 & 31; int k = 4 * c4;
    float4 v = *(const float4*)(v_win + (size_t)(8 * j + r) * 128 + k);
    *(float4*)&w_l1[r][k + 4 * (k >> 6)] = v;
  }
  if (tid < 8) {
    sb_l1[tid] = v_bin[8 * j + tid];
    sb_m0[tid] = v_bmid[8 * j + tid];
    sb_m1[tid] = v_bmid[256 + 8 * j + tid];
  }
  if (tid < 64) sb_l4[tid] = v_bout[64 * j + tid];
  for (int e2 = tid; e2 < 16 * 64; e2 += NTHR) {
    int bb = e2 >> 6, i2 = e2 & 63;
    int b = g * 16 + bb;
    s_ts[bb][i2] = ts[b * 64 + i2];
    s_kn[bb][i2] = tsi[b * 64 + i2];
  }
  if (tid < 16) s_tm[tid] = tmax[g * 16 + tid];
  __syncthreads();

  uint32_t tgt = 0;

  auto stage_act = [&](const float* hsrc) {
    for (int e2 = tid; e2 < 1024; e2 += NTHR) {    // 16 b x 64 f4
      int bb = e2 >> 6, c4 = e2 & 63; int k = 4 * c4;
      float4 v = *(const float4*)(hsrc + bb * 256 + k);
      *(float4*)&s_act[bb][k + 4 * (k >> 6)] = v;
    }
    __syncthreads();
  };

  // 256-in -> 8-row-slice layer, softplus; LDS weights. 16-lane w-broadcast.
  auto mid_phase = [&](const float (*W)[STW], const float* bias, float* hdst) {
    int bb = tid & 15, kh = (tid >> 4) & 1, o = tid >> 5;
    float acc = 0.f;
    const float* wr = &W[o][kh * 136];
    const float* ar = &s_act[bb][kh * 136];
#pragma unroll
    for (int c = 0; c < 32; ++c) {
      int off = 4 * c + 4 * (c >> 4);
      acc = dot4(*(const float4*)(wr + off), *(const float4*)(ar + off), acc);
    }
    acc += __shfl_xor(acc, 16);
    if (kh == 0) hdst[bb * 256 + 8 * j + o] = sp(acc + bias[o]);
  };

  // ---------------- init MLP: y0 = MLP_i(x0), weights from global ----------
  {
    int bb = tid >> 4, d = tid & 15;
    float t0 = s_ts[bb][0];
    int sj = seg_idx(&s_kn[bb][0], t0);
    float k0 = s_kn[bb][sj], k1 = s_kn[bb][sj + 1];
    float fr = (t0 - k0) / (k1 - k0);
    const float* ob = obs + ((size_t)(g * 16 + bb) * 64 + sj) * 16 + d;
    float o0 = ob[0], o1 = ob[16];
    s_y[bb][d] = fmaf(fr, o1 - o0, o0);
  }
  __syncthreads();
  if (tid < 128) {  // L1i: 16-in, 8-row slice
    int bb = tid & 15, o = tid >> 4;
    float acc = i_bin[8 * j + o];
    const float* wr = i_win + (size_t)(8 * j + o) * 16;
#pragma unroll
    for (int i2 = 0; i2 < 16; ++i2) acc = fmaf(wr[i2], s_y[bb][i2], acc);
    h1g[bb * 256 + 8 * j + o] = sp(acc);
  }
  tgt += NJ; gbar(cnt, tgt);
  for (int layer = 0; layer < 2; ++layer) {  // mid-i layers, global weights
    stage_act(layer == 0 ? h1g : h2g);
    int bb = tid & 15, kh = (tid >> 4) & 1, o = tid >> 5;
    float acc = 0.f;
    const float* wr = i_wmid + (size_t)layer * 65536 + (size_t)(8 * j + o) * 256 + kh * 128;
    const float* ar = &s_act[bb][kh * 136];
#pragma unroll
    for (int c = 0; c < 32; ++c) {
      float4 wv = *(const float4*)(wr + 4 * c);
      int off = 4 * c + 4 * (c >> 4);
      acc = dot4(wv, *(const float4*)(ar + off), acc);
    }
    acc += __shfl_xor(acc, 16);
    if (kh == 0) {
      float* hdst = (layer == 0 ? h2g : h3g);
      hdst[bb * 256 + 8 * j + o] = sp(acc + i_bmid[layer * 256 + 8 * j + o]);
    }
    tgt += NJ; gbar(cnt, tgt);
  }
  {  // L4i: 4-row slice of 128-wide y0, identity; commit y0 + out row 0
    stage_act(h3g);
    int bb = tid & 15, kq4 = (tid >> 4) & 3, rl = tid >> 6;
    float acc = 0.f;
    const float* wr = i_wout + (size_t)(4 * j + rl) * 256 + kq4 * 64;
    const float* ar = &s_act[bb][kq4 * 68];
#pragma unroll
    for (int c = 0; c < 16; ++c)
      acc = dot4(*(const float4*)(wr + 4 * c), *(const float4*)(ar + 4 * c), acc);
    acc += __shfl_xor(acc, 16);
    acc += __shfl_xor(acc, 32);
    if (kq4 == 0) {
      int hg = 4 * j + rl;
      float y0 = acc + i_bout[hg];
      yw[bb * 128 + hg] = y0;
      int b = g * 16 + bb;
      out[(size_t)b * 8192 + hg] = (s_ts[bb][0] <= s_tm[bb]) ? y0 : -99.f;
    }
  }
  tgt += NJ; gbar(cnt, tgt);

  // ---------------- RK4 over 63 intervals ----------------
  const int kq = tid & 3, bq = (tid >> 2) & 3, rq = tid >> 4;
  const float* wrow[4];
  const float* arow[4];
#pragma unroll
  for (int i2 = 0; i2 < 4; ++i2) {
    wrow[i2] = &w_l4[4 * rq + i2][kq * 68];
    arow[i2] = &s_act[4 * bq + i2][kq * 68];
  }
  float ka[4] = {0.f, 0.f, 0.f, 0.f};

#pragma unroll 1
  for (int l = 0; l < 63; ++l) {
    const int cur = l & 1, nxt = cur ^ 1;
#pragma unroll 1
    for (int e = 0; e < 4; ++e) {
      {  // prologue: dt (e0), dx(t_e)
        int bb = tid >> 4, d = tid & 15;
        float t0 = s_ts[bb][l], t1 = s_ts[bb][l + 1];
        float dtv = t1 - t0;
        if (e == 0 && d == 0) s_dt[bb] = dtv;
        float te = (e == 0) ? t0 : ((e == 3) ? t1 : fmaf(0.5f, dtv, t0));
        int sj = seg_idx(&s_kn[bb][0], te);
        const float* ob = obs + ((size_t)(g * 16 + bb) * 64 + sj) * 16 + d;
        s_dx[bb][d] = (ob[16] - ob[0]) / (s_kn[bb][sj + 1] - s_kn[bb][sj]);
      }
      {  // stage y_in = y (+ c*dt*k)
        const float* ywc = yw + cur * 2048;
        for (int e2 = tid; e2 < 512; e2 += NTHR) {
          int bb = e2 >> 5, c4 = e2 & 31; int i2 = 4 * c4;
          float4 yv = *(const float4*)(ywc + bb * 128 + i2);
          if (e > 0) {
            float cd = ((e == 3) ? 1.f : 0.5f) * s_dt[bb];
            float4 kv = *(const float4*)(kw + bb * 128 + i2);
            yv.x = fmaf(cd, kv.x, yv.x); yv.y = fmaf(cd, kv.y, yv.y);
            yv.z = fmaf(cd, kv.z, yv.z); yv.w = fmaf(cd, kv.w, yv.w);
          }
          *(float4*)&s_y[bb][i2 + 4 * (i2 >> 6)] = yv;
        }
      }
      __syncthreads();
      {  // L1: 128-in, 8-row slice
        int bb = tid & 15, kh = (tid >> 4) & 1, o = tid >> 5;
        float acc = 0.f;
        const float* wr = &w_l1[o][kh * 68];
        const float* ar = &s_y[bb][kh * 68];
#pragma unroll
        for (int c = 0; c < 16; ++c)
          acc = dot4(*(const float4*)(wr + 4 * c), *(const float4*)(ar + 4 * c), acc);
        acc += __shfl_xor(acc, 16);
        if (kh == 0) h1g[bb * 256 + 8 * j + o] = sp(acc + sb_l1[o]);
      }
      tgt += NJ; gbar(cnt, tgt);
      stage_act(h1g); mid_phase(w_m0, sb_m0, h2g); tgt += NJ; gbar(cnt, tgt);
      stage_act(h2g); mid_phase(w_m1, sb_m1, h3g); tgt += NJ; gbar(cnt, tgt);
      stage_act(h3g);
      {  // L4: 64-row slice, 4r x 4b x kq blocking; tanh; dx-contract; commit
        float acc[4][4] = {};
#pragma unroll
        for (int c = 0; c < 16; ++c) {
          float4 wv[4], av[4];
#pragma unroll
          for (int i2 = 0; i2 < 4; ++i2) wv[i2] = *(const float4*)(wrow[i2] + 4 * c);
#pragma unroll
          for (int b2 = 0; b2 < 4; ++b2) av[b2] = *(const float4*)(arow[b2] + 4 * c);
#pragma unroll
          for (int i2 = 0; i2 < 4; ++i2)
#pragma unroll
            for (int b2 = 0; b2 < 4; ++b2)
              acc[i2][b2] = dot4(wv[i2], av[b2], acc[i2][b2]);
        }
#pragma unroll
        for (int i2 = 0; i2 < 4; ++i2)
#pragma unroll
          for (int b2 = 0; b2 < 4; ++b2) {
            acc[i2][b2] += __shfl_xor(acc[i2][b2], 1);
            acc[i2][b2] += __shfl_xor(acc[i2][b2], 2);
          }
        const int q = rq & 3, hloc = rq >> 2;
        float kb[4];
#pragma unroll
        for (int b2 = 0; b2 < 4; ++b2) {
          float s = 0.f;
#pragma unroll
          for (int i2 = 0; i2 < 4; ++i2) {
            float z = acc[i2][b2] + sb_l4[4 * rq + i2];
            s = fmaf(tanhf(z), s_dx[4 * bq + b2][4 * q + i2], s);
          }
          kb[b2] = s;
        }
#pragma unroll
        for (int b2 = 0; b2 < 4; ++b2) {
          kb[b2] += __shfl_xor(kb[b2], 16);
          kb[b2] += __shfl_xor(kb[b2], 32);
        }
        const int hg = 4 * j + hloc;
        if (kq == 0 && q == 0) {
#pragma unroll
          for (int b2 = 0; b2 < 4; ++b2) {
            int bb = 4 * bq + b2;
            kw[bb * 128 + hg] = kb[b2];
            if (e == 0) ka[b2] = kb[b2];
            else ka[b2] = fmaf((e == 3) ? 1.f : 2.f, kb[b2], ka[b2]);
            if (e == 3) {
              float dt = s_dt[bb];
              float yn = yw[cur * 2048 + bb * 128 + hg] + dt * (1.f / 6.f) * ka[b2];
              yw[nxt * 2048 + bb * 128 + hg] = yn;
              int b = g * 16 + bb;
              out[(size_t)b * 8192 + (size_t)(l + 1) * 128 + hg] =
                  (s_ts[bb][l + 1] <= s_tm[bb]) ? yn : -99.f;
            }
          }
        }
      }
      tgt += NJ; gbar(cnt, tgt);
    }
  }
}

extern "C" void kernel_launch(void* const* d_in, const int* in_sizes, int n_in,
                              void* d_out, int out_size, void* d_ws, size_t ws_size,
                              hipStream_t stream) {
  const float* ts     = (const float*)d_in[0];
  const float* tsi    = (const float*)d_in[1];
  const float* obs    = (const float*)d_in[2];
  const float* tmaxp  = (const float*)d_in[3];
  const float* i_win  = (const float*)d_in[4];
  const float* i_bin  = (const float*)d_in[5];
  const float* i_wmid = (const float*)d_in[6];
  const float* i_bmid = (const float*)d_in[7];
  const float* i_wout = (const float*)d_in[8];
  const float* i_bout = (const float*)d_in[9];
  const float* v_win  = (const float*)d_in[10];
  const float* v_bin  = (const float*)d_in[11];
  const float* v_wmid = (const float*)d_in[12];
  const float* v_bmid = (const float*)d_in[13];
  const float* v_wout = (const float*)d_in[14];
  const float* v_bout = (const float*)d_in[15];

  // zero the group barrier counters each launch (graph-capture safe)
  (void)hipMemsetAsync(d_ws, 0, 2048, stream);

  ncde_kernel<<<dim3(NGRP * NJ), dim3(NTHR), 0, stream>>>(
      ts, tsi, obs, tmaxp,
      i_win, i_bin, i_wmid, i_bmid, i_wout, i_bout,
      v_win, v_bin, v_wmid, v_bmid, v_wout, v_bout,
      (float*)d_out, (uint32_t*)d_ws);
}

// Round 3
// 6295.827 us; speedup vs baseline: 1.8983x; 1.8983x over previous
//
#include <hip/hip_runtime.h>
#include <stdint.h>

// Online Neural CDE, fused persistent kernel — full fp32 datapath.
// 8 groups x 32 blocks; group = 16 batches; each block holds a 1/32
// output-row-slice of every vector-field weight matrix in LDS (fp32).
// Cross-block exchange via FINE-GRAINED agent-scope (sc1) atomics through
// the Infinity Cache — no cache-wide fences anywhere in the loop.

#define NGRP 8
#define NJ   32
#define NTHR 256
#define STW  276   // dword stride for 256-col tiles (4-dword gap per 64 cols)
#define STY  132   // dword stride for 128-col y tile (gap at col 64)

typedef unsigned long long u64t;

static __device__ __forceinline__ u64t ld_coh8(const u64t* p) {
  return __hip_atomic_load(p, __ATOMIC_RELAXED, __HIP_MEMORY_SCOPE_AGENT);
}
static __device__ __forceinline__ void st_coh4(float* p, float v) {
  __hip_atomic_store(p, v, __ATOMIC_RELAXED, __HIP_MEMORY_SCOPE_AGENT);
}

// jax.nn.softplus(x) = max(x,0) + log1p(exp(-|x|))
static __device__ __forceinline__ float sp(float x) {
  return fmaxf(x, 0.f) + log1pf(expf(-fabsf(x)));
}

// np.searchsorted(kn, t, 'right') - 1, clipped to [0, 62]; 64 knots.
static __device__ __forceinline__ int seg_idx(const float* kn, float t) {
  int lo = 0, hi = 64;
  while (lo < hi) { int mid = (lo + hi) >> 1; if (kn[mid] <= t) lo = mid + 1; else hi = mid; }
  int jj = lo - 1;
  return jj < 0 ? 0 : (jj > 62 ? 62 : jj);
}

static __device__ __forceinline__ float dot4(float4 w, float4 a, float acc) {
  acc = fmaf(w.x, a.x, acc);
  acc = fmaf(w.y, a.y, acc);
  acc = fmaf(w.z, a.z, acc);
  return fmaf(w.w, a.w, acc);
}

// Group barrier: monotonic epoch, 4 sub-counters (256B apart) per group.
// All payload traffic is sc1 (agent-coherent per access), so the only
// ordering needed is vmcnt(0) before the signal — no cache maintenance.
static __device__ __forceinline__ void gbar(uint32_t* cbase, int sub, uint32_t target) {
  asm volatile("s_waitcnt vmcnt(0)" ::: "memory");  // per-wave: payload stores visible
  __syncthreads();                                   // all waves drained
  if (threadIdx.x == 0) {
    __hip_atomic_fetch_add(cbase + sub * 64, 1u, __ATOMIC_RELAXED, __HIP_MEMORY_SCOPE_AGENT);
    uint32_t it = 0;
    for (;;) {
      uint32_t s = 0;
#pragma unroll
      for (int q = 0; q < 4; ++q)
        s += __hip_atomic_load(cbase + q * 64, __ATOMIC_RELAXED, __HIP_MEMORY_SCOPE_AGENT);
      if (s >= target) break;
      __builtin_amdgcn_s_sleep(1);
      if (++it > (1u << 20)) break;  // failsafe (surfaces as wrong output, not hang)
    }
  }
  __syncthreads();
}

__global__ void __launch_bounds__(NTHR)
ncde_kernel(const float* __restrict__ ts, const float* __restrict__ tsi,
            const float* __restrict__ obs, const float* __restrict__ tmax,
            const float* __restrict__ i_win, const float* __restrict__ i_bin,
            const float* __restrict__ i_wmid, const float* __restrict__ i_bmid,
            const float* __restrict__ i_wout, const float* __restrict__ i_bout,
            const float* __restrict__ v_win, const float* __restrict__ v_bin,
            const float* __restrict__ v_wmid, const float* __restrict__ v_bmid,
            const float* __restrict__ v_wout, const float* __restrict__ v_bout,
            float* __restrict__ out, uint32_t* __restrict__ ws)
{
  __shared__ __align__(16) float w_l4[64][STW];   // v_wout rows 64j..64j+63
  __shared__ __align__(16) float w_m0[8][STW];    // v_wmid[0] rows 8j..
  __shared__ __align__(16) float w_m1[8][STW];    // v_wmid[1] rows 8j..
  __shared__ __align__(16) float w_l1[8][STY];    // v_win rows 8j..
  __shared__ __align__(16) float s_act[16][STW];  // staged 256-wide activations
  __shared__ __align__(16) float s_y[16][STY];    // staged 128-wide y input
  __shared__ __align__(16) float s_ts[16][64];
  __shared__ __align__(16) float s_kn[16][64];
  __shared__ float s_dx[16][16];
  __shared__ float s_dt[16], s_tm[16];
  __shared__ float sb_l1[8], sb_m0[8], sb_m1[8], sb_l4[64];

  const int tid = threadIdx.x;
  const int bid = blockIdx.x;
  const int g = bid & 7;    // group (== XCD under round-robin; perf heuristic only)
  const int j = bid >> 3;   // slice 0..31
  const int sub = j & 3;    // barrier sub-counter

  uint32_t* cbase = ws + (size_t)g * 256;   // 4 sub-counters, 256B apart (1KB/group)
  float* base = (float*)(ws + 2048) + (size_t)g * 20480;
  float* yw  = base;          // [2][16][128]
  float* kw  = base + 4096;   // [16][128]
  float* h1g = base + 6144;   // [16][256]
  float* h2g = base + 10240;
  float* h3g = base + 14336;

  // ---------------- load weight slices -> LDS (fp32, gapped cols) ----------
  for (int e2 = tid; e2 < 64 * 64; e2 += NTHR) {   // w_l4: 64 rows x 64 f4
    int r = e2 >> 6, c4 = e2 & 63; int k = 4 * c4;
    float4 v = *(const float4*)(v_wout + (size_t)(64 * j + r) * 256 + k);
    *(float4*)&w_l4[r][k + 4 * (k >> 6)] = v;
  }
  for (int e2 = tid; e2 < 8 * 64; e2 += NTHR) {    // mids: 8 rows x 64 f4 each
    int r = e2 >> 6, c4 = e2 & 63; int k = 4 * c4;
    float4 a = *(const float4*)(v_wmid + (size_t)(8 * j + r) * 256 + k);
    float4 b2 = *(const float4*)(v_wmid + 65536 + (size_t)(8 * j + r) * 256 + k);
    int col = k + 4 * (k >> 6);
    *(float4*)&w_m0[r][col] = a;
    *(float4*)&w_m1[r][col] = b2;
  }
  {                                                // w_l1: 8 rows x 32 f4
    int e2 = tid; int r = e2 >> 5, c4 = e2 & 31; int k = 4 * c4;
    float4 v = *(const float4*)(v_win + (size_t)(8 * j + r) * 128 + k);
    *(float4*)&w_l1[r][k + 4 * (k >> 6)] = v;
  }
  if (tid < 8) {
    sb_l1[tid] = v_bin[8 * j + tid];
    sb_m0[tid] = v_bmid[8 * j + tid];
    sb_m1[tid] = v_bmid[256 + 8 * j + tid];
  }
  if (tid < 64) sb_l4[tid] = v_bout[64 * j + tid];
  for (int e2 = tid; e2 < 16 * 64; e2 += NTHR) {
    int bb = e2 >> 6, i2 = e2 & 63;
    int b = g * 16 + bb;
    s_ts[bb][i2] = ts[b * 64 + i2];
    s_kn[bb][i2] = tsi[b * 64 + i2];
  }
  if (tid < 16) s_tm[tid] = tmax[g * 16 + tid];
  __syncthreads();

  uint32_t tgt = 0;

  // stage 256-wide activations (agent-coherent loads) -> gapped LDS
  auto stage_act = [&](const float* hsrc) {
    const u64t* hp = (const u64t*)hsrc;            // [16][128] u64
    for (int e2 = tid; e2 < 2048; e2 += NTHR) {    // 8 per thread
      int bb = e2 >> 7, c2 = e2 & 127;
      u64t v = ld_coh8(hp + bb * 128 + c2);
      int k = 2 * c2;
      *(u64t*)&s_act[bb][k + 4 * (k >> 6)] = v;    // k even -> 8B aligned
    }
    __syncthreads();
  };

  // 256-in -> 8-row-slice layer, softplus; LDS weights. 16-lane w-broadcast.
  auto mid_phase = [&](const float (*W)[STW], const float* bias, float* hdst) {
    int bb = tid & 15, kh = (tid >> 4) & 1, o = tid >> 5;
    float acc = 0.f;
    const float* wr = &W[o][kh * 136];
    const float* ar = &s_act[bb][kh * 136];
#pragma unroll
    for (int c = 0; c < 32; ++c) {
      int off = 4 * c + 4 * (c >> 4);
      acc = dot4(*(const float4*)(wr + off), *(const float4*)(ar + off), acc);
    }
    acc += __shfl_xor(acc, 16);
    if (kh == 0) st_coh4(&hdst[bb * 256 + 8 * j + o], sp(acc + bias[o]));
  };

  // ---------------- init MLP: y0 = MLP_i(x0), weights from global ----------
  {
    int bb = tid >> 4, d = tid & 15;
    float t0 = s_ts[bb][0];
    int sj = seg_idx(&s_kn[bb][0], t0);
    float k0 = s_kn[bb][sj], k1 = s_kn[bb][sj + 1];
    float fr = (t0 - k0) / (k1 - k0);
    const float* ob = obs + ((size_t)(g * 16 + bb) * 64 + sj) * 16 + d;
    float o0 = ob[0], o1 = ob[16];
    s_y[bb][d] = fmaf(fr, o1 - o0, o0);
  }
  __syncthreads();
  if (tid < 128) {  // L1i: 16-in, 8-row slice
    int bb = tid & 15, o = tid >> 4;
    float acc = i_bin[8 * j + o];
    const float* wr = i_win + (size_t)(8 * j + o) * 16;
#pragma unroll
    for (int i2 = 0; i2 < 16; ++i2) acc = fmaf(wr[i2], s_y[bb][i2], acc);
    st_coh4(&h1g[bb * 256 + 8 * j + o], sp(acc));
  }
  tgt += NJ; gbar(cbase, sub, tgt);
  for (int layer = 0; layer < 2; ++layer) {  // mid-i layers, global weights
    stage_act(layer == 0 ? h1g : h2g);
    int bb = tid & 15, kh = (tid >> 4) & 1, o = tid >> 5;
    float acc = 0.f;
    const float* wr = i_wmid + (size_t)layer * 65536 + (size_t)(8 * j + o) * 256 + kh * 128;
    const float* ar = &s_act[bb][kh * 136];
#pragma unroll
    for (int c = 0; c < 32; ++c) {
      float4 wv = *(const float4*)(wr + 4 * c);
      int off = 4 * c + 4 * (c >> 4);
      acc = dot4(wv, *(const float4*)(ar + off), acc);
    }
    acc += __shfl_xor(acc, 16);
    if (kh == 0) {
      float* hdst = (layer == 0 ? h2g : h3g);
      st_coh4(&hdst[bb * 256 + 8 * j + o], sp(acc + i_bmid[layer * 256 + 8 * j + o]));
    }
    tgt += NJ; gbar(cbase, sub, tgt);
  }
  {  // L4i: 4-row slice of 128-wide y0, identity; commit y0 + out row 0
    stage_act(h3g);
    int bb = tid & 15, kq4 = (tid >> 4) & 3, rl = tid >> 6;
    float acc = 0.f;
    const float* wr = i_wout + (size_t)(4 * j + rl) * 256 + kq4 * 64;
    const float* ar = &s_act[bb][kq4 * 68];
#pragma unroll
    for (int c = 0; c < 16; ++c)
      acc = dot4(*(const float4*)(wr + 4 * c), *(const float4*)(ar + 4 * c), acc);
    acc += __shfl_xor(acc, 16);
    acc += __shfl_xor(acc, 32);
    if (kq4 == 0) {
      int hg = 4 * j + rl;
      float y0 = acc + i_bout[hg];
      st_coh4(&yw[bb * 128 + hg], y0);
      int b = g * 16 + bb;
      out[(size_t)b * 8192 + hg] = (s_ts[bb][0] <= s_tm[bb]) ? y0 : -99.f;
    }
  }
  tgt += NJ; gbar(cbase, sub, tgt);

  // ---------------- RK4 over 63 intervals ----------------
  const int kq = tid & 3, bq = (tid >> 2) & 3, rq = tid >> 4;
  const float* wrow[4];
  const float* arow[4];
#pragma unroll
  for (int i2 = 0; i2 < 4; ++i2) {
    wrow[i2] = &w_l4[4 * rq + i2][kq * 68];
    arow[i2] = &s_act[4 * bq + i2][kq * 68];
  }
  float ka[4] = {0.f, 0.f, 0.f, 0.f};

#pragma unroll 1
  for (int l = 0; l < 63; ++l) {
    const int cur = l & 1, nxt = cur ^ 1;
#pragma unroll 1
    for (int e = 0; e < 4; ++e) {
      {  // prologue: dt (e0), dx(t_e) — block-local, LDS only
        int bb = tid >> 4, d = tid & 15;
        float t0 = s_ts[bb][l], t1 = s_ts[bb][l + 1];
        float dtv = t1 - t0;
        if (e == 0 && d == 0) s_dt[bb] = dtv;
        float te = (e == 0) ? t0 : ((e == 3) ? t1 : fmaf(0.5f, dtv, t0));
        int sj = seg_idx(&s_kn[bb][0], te);
        const float* ob = obs + ((size_t)(g * 16 + bb) * 64 + sj) * 16 + d;
        s_dx[bb][d] = (ob[16] - ob[0]) / (s_kn[bb][sj + 1] - s_kn[bb][sj]);
      }
      {  // stage y_in = y (+ c*dt*k); sc1 loads (s_dt written at e==0, read e>0: safe)
        const u64t* ywc = (const u64t*)(yw + cur * 2048);
        const u64t* kwp = (const u64t*)kw;
        for (int e2 = tid; e2 < 1024; e2 += NTHR) {
          int bb = e2 >> 6, c2 = e2 & 63;
          float2 yv = __builtin_bit_cast(float2, ld_coh8(ywc + bb * 64 + c2));
          if (e > 0) {
            float cd = ((e == 3) ? 1.f : 0.5f) * s_dt[bb];
            float2 kv = __builtin_bit_cast(float2, ld_coh8(kwp + bb * 64 + c2));
            yv.x = fmaf(cd, kv.x, yv.x);
            yv.y = fmaf(cd, kv.y, yv.y);
          }
          int i2 = 2 * c2;
          *(float2*)&s_y[bb][i2 + 4 * (i2 >> 6)] = yv;
        }
      }
      __syncthreads();
      {  // L1: 128-in, 8-row slice
        int bb = tid & 15, kh = (tid >> 4) & 1, o = tid >> 5;
        float acc = 0.f;
        const float* wr = &w_l1[o][kh * 68];
        const float* ar = &s_y[bb][kh * 68];
#pragma unroll
        for (int c = 0; c < 16; ++c)
          acc = dot4(*(const float4*)(wr + 4 * c), *(const float4*)(ar + 4 * c), acc);
        acc += __shfl_xor(acc, 16);
        if (kh == 0) st_coh4(&h1g[bb * 256 + 8 * j + o], sp(acc + sb_l1[o]));
      }
      tgt += NJ; gbar(cbase, sub, tgt);
      stage_act(h1g); mid_phase(w_m0, sb_m0, h2g); tgt += NJ; gbar(cbase, sub, tgt);
      stage_act(h2g); mid_phase(w_m1, sb_m1, h3g); tgt += NJ; gbar(cbase, sub, tgt);
      stage_act(h3g);
      {  // L4: 64-row slice, 4r x 4b x kq blocking; tanh; dx-contract; commit
        float acc[4][4] = {};
#pragma unroll
        for (int c = 0; c < 16; ++c) {
          float4 wv[4], av[4];
#pragma unroll
          for (int i2 = 0; i2 < 4; ++i2) wv[i2] = *(const float4*)(wrow[i2] + 4 * c);
#pragma unroll
          for (int b2 = 0; b2 < 4; ++b2) av[b2] = *(const float4*)(arow[b2] + 4 * c);
#pragma unroll
          for (int i2 = 0; i2 < 4; ++i2)
#pragma unroll
            for (int b2 = 0; b2 < 4; ++b2)
              acc[i2][b2] = dot4(wv[i2], av[b2], acc[i2][b2]);
        }
#pragma unroll
        for (int i2 = 0; i2 < 4; ++i2)
#pragma unroll
          for (int b2 = 0; b2 < 4; ++b2) {
            acc[i2][b2] += __shfl_xor(acc[i2][b2], 1);
            acc[i2][b2] += __shfl_xor(acc[i2][b2], 2);
          }
        const int q = rq & 3, hloc = rq >> 2;
        float kb[4];
#pragma unroll
        for (int b2 = 0; b2 < 4; ++b2) {
          float s = 0.f;
#pragma unroll
          for (int i2 = 0; i2 < 4; ++i2) {
            float z = acc[i2][b2] + sb_l4[4 * rq + i2];
            s = fmaf(tanhf(z), s_dx[4 * bq + b2][4 * q + i2], s);
          }
          kb[b2] = s;
        }
#pragma unroll
        for (int b2 = 0; b2 < 4; ++b2) {
          kb[b2] += __shfl_xor(kb[b2], 16);
          kb[b2] += __shfl_xor(kb[b2], 32);
        }
        const int hg = 4 * j + hloc;
        if (kq == 0 && q == 0) {
#pragma unroll
          for (int b2 = 0; b2 < 4; ++b2) {
            int bb = 4 * bq + b2;
            st_coh4(&kw[bb * 128 + hg], kb[b2]);
            if (e == 0) ka[b2] = kb[b2];
            else ka[b2] = fmaf((e == 3) ? 1.f : 2.f, kb[b2], ka[b2]);
            if (e == 3) {
              float dt = s_dt[bb];
              float yn = yw[cur * 2048 + bb * 128 + hg] + dt * (1.f / 6.f) * ka[b2];
              st_coh4(&yw[nxt * 2048 + bb * 128 + hg], yn);
              int b = g * 16 + bb;
              out[(size_t)b * 8192 + (size_t)(l + 1) * 128 + hg] =
                  (s_ts[bb][l + 1] <= s_tm[bb]) ? yn : -99.f;
            }
          }
        }
      }
      tgt += NJ; gbar(cbase, sub, tgt);
    }
  }
}

extern "C" void kernel_launch(void* const* d_in, const int* in_sizes, int n_in,
                              void* d_out, int out_size, void* d_ws, size_t ws_size,
                              hipStream_t stream) {
  const float* ts     = (const float*)d_in[0];
  const float* tsi    = (const float*)d_in[1];
  const float* obs    = (const float*)d_in[2];
  const float* tmaxp  = (const float*)d_in[3];
  const float* i_win  = (const float*)d_in[4];
  const float* i_bin  = (const float*)d_in[5];
  const float* i_wmid = (const float*)d_in[6];
  const float* i_bmid = (const float*)d_in[7];
  const float* i_wout = (const float*)d_in[8];
  const float* i_bout = (const float*)d_in[9];
  const float* v_win  = (const float*)d_in[10];
  const float* v_bin  = (const float*)d_in[11];
  const float* v_wmid = (const float*)d_in[12];
  const float* v_bmid = (const float*)d_in[13];
  const float* v_wout = (const float*)d_in[14];
  const float* v_bout = (const float*)d_in[15];

  // zero the 8 groups x 4 sub-counters (8KB) each launch (graph-capture safe)
  (void)hipMemsetAsync(d_ws, 0, 8192, stream);

  ncde_kernel<<<dim3(NGRP * NJ), dim3(NTHR), 0, stream>>>(
      ts, tsi, obs, tmaxp,
      i_win, i_bin, i_wmid, i_bmid, i_wout, i_bout,
      v_win, v_bin, v_wmid, v_bmid, v_wout, v_bout,
      (float*)d_out, (uint32_t*)d_ws);
}

// Round 4
// 6122.277 us; speedup vs baseline: 1.9521x; 1.0283x over previous
//
#include <hip/hip_runtime.h>
#include <stdint.h>

// Online Neural CDE, fused persistent kernel — fp32 datapath, two-set pipeline.
// 8 groups x 32 blocks; group = 16 batches, split into sets A(0-7)/B(8-15).
// Each block holds a 1/32 output-row-slice of the vector-field weights in LDS.
// Cross-block exchange via fine-grained agent-scope (sc1) loads/stores through
// the Infinity Cache. Group sync via per-block epoch FLAGS (no atomics); the
// two sets' layer chains are interleaved so every inter-block wait is covered
// by the other set's compute.

#define NGRP 8
#define NJ   32
#define NTHR 256
#define STW  276   // dword stride for 256-col tiles (4-dword gap per 64 cols)
#define STY  132   // dword stride for 128-col y tile (gap at col 64)

typedef unsigned long long u64t;

static __device__ __forceinline__ u64t ld_coh8(const u64t* p) {
  return __hip_atomic_load(p, __ATOMIC_RELAXED, __HIP_MEMORY_SCOPE_AGENT);
}
static __device__ __forceinline__ float ld_coh4(const float* p) {
  return __hip_atomic_load(p, __ATOMIC_RELAXED, __HIP_MEMORY_SCOPE_AGENT);
}
static __device__ __forceinline__ void st_coh4(float* p, float v) {
  __hip_atomic_store(p, v, __ATOMIC_RELAXED, __HIP_MEMORY_SCOPE_AGENT);
}

// jax.nn.softplus(x) = max(x,0) + log1p(exp(-|x|))
static __device__ __forceinline__ float sp(float x) {
  return fmaxf(x, 0.f) + log1pf(expf(-fabsf(x)));
}

// np.searchsorted(kn, t, 'right') - 1, clipped to [0, 62]; 64 knots.
static __device__ __forceinline__ int seg_idx(const float* kn, float t) {
  int lo = 0, hi = 64;
  while (lo < hi) { int mid = (lo + hi) >> 1; if (kn[mid] <= t) lo = mid + 1; else hi = mid; }
  int jj = lo - 1;
  return jj < 0 ? 0 : (jj > 62 ? 62 : jj);
}

static __device__ __forceinline__ float dot4(float4 w, float4 a, float acc) {
  acc = fmaf(w.x, a.x, acc);
  acc = fmaf(w.y, a.y, acc);
  acc = fmaf(w.z, a.z, acc);
  return fmaf(w.w, a.w, acc);
}

__global__ void __launch_bounds__(NTHR)
ncde_kernel(const float* __restrict__ ts, const float* __restrict__ tsi,
            const float* __restrict__ obs, const float* __restrict__ tmax,
            const float* __restrict__ i_win, const float* __restrict__ i_bin,
            const float* __restrict__ i_wmid, const float* __restrict__ i_bmid,
            const float* __restrict__ i_wout, const float* __restrict__ i_bout,
            const float* __restrict__ v_win, const float* __restrict__ v_bin,
            const float* __restrict__ v_wmid, const float* __restrict__ v_bmid,
            const float* __restrict__ v_wout, const float* __restrict__ v_bout,
            float* __restrict__ out, uint32_t* __restrict__ ws)
{
  __shared__ __align__(16) float w_l4[64][STW];   // v_wout rows 64j..64j+63
  __shared__ __align__(16) float w_m0[8][STW];    // v_wmid[0] rows 8j..
  __shared__ __align__(16) float w_m1[8][STW];    // v_wmid[1] rows 8j..
  __shared__ __align__(16) float w_l1[8][STY];    // v_win rows 8j..
  __shared__ __align__(16) float s_act[16][STW];  // staged activations (rows 8s..)
  __shared__ __align__(16) float s_y[16][STY];    // staged y input (rows 8s..)
  __shared__ __align__(16) float s_ts[16][64];
  __shared__ __align__(16) float s_kn[16][64];
  __shared__ float s_dx[16][16];
  __shared__ float s_dt[16], s_tm[16];
  __shared__ float sb_l1[8], sb_m0[8], sb_m1[8], sb_l4[64];

  const int tid = threadIdx.x;
  const int bid = blockIdx.x;
  const int g = bid & 7;    // group (== XCD under round-robin; perf heuristic only)
  const int j = bid >> 3;   // slice 0..31

  // epoch flags: per group, per set, one dword per block (64-dword spacing/set)
  uint32_t* flagA = ws + (size_t)(g * 2 + 0) * 64;
  uint32_t* flagB = ws + (size_t)(g * 2 + 1) * 64;
  float* base = (float*)(ws + 1024) + (size_t)g * 18432;
  float* yw = base;           // [2][16][128]
  float* kw = base + 4096;    // [16][128]
  float* h1 = base + 6144;    // [16][256]
  float* h2 = base + 10240;
  float* h3 = base + 14336;

  // ---------------- load weight slices -> LDS (fp32, gapped cols) ----------
  for (int e2 = tid; e2 < 64 * 64; e2 += NTHR) {   // w_l4: 64 rows x 64 f4
    int r = e2 >> 6, c4 = e2 & 63; int k = 4 * c4;
    float4 v = *(const float4*)(v_wout + (size_t)(64 * j + r) * 256 + k);
    *(float4*)&w_l4[r][k + 4 * (k >> 6)] = v;
  }
  for (int e2 = tid; e2 < 8 * 64; e2 += NTHR) {    // mids: 8 rows x 64 f4 each
    int r = e2 >> 6, c4 = e2 & 63; int k = 4 * c4;
    float4 a = *(const float4*)(v_wmid + (size_t)(8 * j + r) * 256 + k);
    float4 b2 = *(const float4*)(v_wmid + 65536 + (size_t)(8 * j + r) * 256 + k);
    int col = k + 4 * (k >> 6);
    *(float4*)&w_m0[r][col] = a;
    *(float4*)&w_m1[r][col] = b2;
  }
  {                                                // w_l1: 8 rows x 32 f4
    int e2 = tid; int r = e2 >> 5, c4 = e2 & 31; int k = 4 * c4;
    float4 v = *(const float4*)(v_win + (size_t)(8 * j + r) * 128 + k);
    *(float4*)&w_l1[r][k + 4 * (k >> 6)] = v;
  }
  if (tid < 8) {
    sb_l1[tid] = v_bin[8 * j + tid];
    sb_m0[tid] = v_bmid[8 * j + tid];
    sb_m1[tid] = v_bmid[256 + 8 * j + tid];
  }
  if (tid < 64) sb_l4[tid] = v_bout[64 * j + tid];
  for (int e2 = tid; e2 < 16 * 64; e2 += NTHR) {
    int bb = e2 >> 6, i2 = e2 & 63;
    int b = g * 16 + bb;
    s_ts[bb][i2] = ts[b * 64 + i2];
    s_kn[bb][i2] = tsi[b * 64 + i2];
  }
  if (tid < 16) s_tm[tid] = tmax[g * 16 + tid];
  __syncthreads();

  uint32_t epA = 0, epB = 0;

  auto signal = [&](uint32_t* flg, uint32_t ep) {
    asm volatile("s_waitcnt vmcnt(0)" ::: "memory");  // this wave's stores visible
    __syncthreads();                                   // all waves drained
    if (tid == 0)
      __hip_atomic_store(flg + j, ep, __ATOMIC_RELAXED, __HIP_MEMORY_SCOPE_AGENT);
  };
  auto wait = [&](uint32_t* flg, uint32_t ep) {
    if (tid < 64) {
      uint32_t it = 0;
      for (;;) {
        uint32_t f = __hip_atomic_load(flg + (tid & 31), __ATOMIC_RELAXED,
                                       __HIP_MEMORY_SCOPE_AGENT);
        if (__all((int)(f >= ep))) break;
        __builtin_amdgcn_s_sleep(1);
        if (++it > (1u << 20)) break;  // failsafe: no hang (surfaces as bad data)
      }
    }
    __syncthreads();
  };

  // stage 8 batches x 256 acts (sc1) -> gapped LDS rows 8s..8s+7
  auto stageH = [&](int s, const float* hsrc) {
    const u64t* hp = (const u64t*)(hsrc + s * 2048);
#pragma unroll
    for (int it = 0; it < 4; ++it) {
      int e2 = tid + it * NTHR;
      int bb = e2 >> 7, c2 = e2 & 127;
      u64t v = ld_coh8(hp + bb * 128 + c2);
      int k = 2 * c2;
      *(u64t*)&s_act[8 * s + bb][k + 4 * (k >> 6)] = v;
    }
    __syncthreads();
  };

  // L1: 128-in (s_y) -> 8-row slice, softplus. (bb8, kq4 of 32 cols, o8)
  auto L1f = [&](int s) {
    int bb = tid & 7, kq = (tid >> 3) & 3, o = tid >> 5;
    int off = kq * 32 + (kq >> 1) * 4;
    float acc = 0.f;
    const float* wr = &w_l1[o][off];
    const float* ar = &s_y[8 * s + bb][off];
#pragma unroll
    for (int c = 0; c < 8; ++c)
      acc = dot4(*(const float4*)(wr + 4 * c), *(const float4*)(ar + 4 * c), acc);
    acc += __shfl_xor(acc, 8);
    acc += __shfl_xor(acc, 16);
    if (kq == 0) st_coh4(&h1[s * 2048 + bb * 256 + 8 * j + o], sp(acc + sb_l1[o]));
  };

  // mid: 256-in (s_act) -> 8-row slice, softplus. (bb8, kq4 of 64 cols, o8)
  auto midf = [&](int s, const float (*W)[STW], const float* bias, float* hdst) {
    int bb = tid & 7, kq = (tid >> 3) & 3, o = tid >> 5;
    float acc = 0.f;
    const float* wr = &W[o][kq * 68];
    const float* ar = &s_act[8 * s + bb][kq * 68];
#pragma unroll
    for (int c = 0; c < 16; ++c)
      acc = dot4(*(const float4*)(wr + 4 * c), *(const float4*)(ar + 4 * c), acc);
    acc += __shfl_xor(acc, 8);
    acc += __shfl_xor(acc, 16);
    if (kq == 0) st_coh4(&hdst[s * 2048 + bb * 256 + 8 * j + o], sp(acc + bias[o]));
  };

  // stage y_in = y (+ c*dt*k) for one set
  auto stageY = [&](int s, int cur, int e) {
    const u64t* ywc = (const u64t*)(yw + cur * 2048 + s * 1024);
    const u64t* kwp = (const u64t*)(kw + s * 1024);
#pragma unroll
    for (int it = 0; it < 2; ++it) {
      int e2 = tid + it * NTHR;
      int bb = e2 >> 6, c2 = e2 & 63;
      float2 yv = __builtin_bit_cast(float2, ld_coh8(ywc + bb * 64 + c2));
      if (e > 0) {
        float cd = ((e == 3) ? 1.f : 0.5f) * s_dt[8 * s + bb];
        float2 kv = __builtin_bit_cast(float2, ld_coh8(kwp + bb * 64 + c2));
        yv.x = fmaf(cd, kv.x, yv.x);
        yv.y = fmaf(cd, kv.y, yv.y);
      }
      int i2 = 2 * c2;
      *(float2*)&s_y[8 * s + bb][i2 + 4 * (i2 >> 6)] = yv;
    }
  };

  // L4: 64-row slice; (kq4 of 64 cols, bq4 of 2 batches, rq16 of 4 rows).
  auto L4f = [&](int s, int e, int cur, int nxt, int l,
                 float& ka0, float& ka1) {
    const int kq = tid & 3, bq = (tid >> 2) & 3, rq = tid >> 4;
    const float* wr0 = &w_l4[4 * rq][kq * 68];
    const float* ar0 = &s_act[8 * s + 2 * bq][kq * 68];
    float acc[4][2] = {};
#pragma unroll
    for (int c = 0; c < 16; ++c) {
      float4 wv[4], av[2];
#pragma unroll
      for (int i2 = 0; i2 < 4; ++i2) wv[i2] = *(const float4*)(wr0 + i2 * STW + 4 * c);
#pragma unroll
      for (int b2 = 0; b2 < 2; ++b2) av[b2] = *(const float4*)(ar0 + b2 * STW + 4 * c);
#pragma unroll
      for (int i2 = 0; i2 < 4; ++i2)
#pragma unroll
        for (int b2 = 0; b2 < 2; ++b2)
          acc[i2][b2] = dot4(wv[i2], av[b2], acc[i2][b2]);
    }
#pragma unroll
    for (int i2 = 0; i2 < 4; ++i2)
#pragma unroll
      for (int b2 = 0; b2 < 2; ++b2) {
        acc[i2][b2] += __shfl_xor(acc[i2][b2], 1);
        acc[i2][b2] += __shfl_xor(acc[i2][b2], 2);
      }
    const int q = rq & 3, hloc = rq >> 2;
    float kb[2];
#pragma unroll
    for (int b2 = 0; b2 < 2; ++b2) {
      float sacc = 0.f;
      int bb = 8 * s + 2 * bq + b2;
#pragma unroll
      for (int i2 = 0; i2 < 4; ++i2) {
        float z = acc[i2][b2] + sb_l4[4 * rq + i2];
        sacc = fmaf(tanhf(z), s_dx[bb][4 * q + i2], sacc);
      }
      kb[b2] = sacc;
    }
#pragma unroll
    for (int b2 = 0; b2 < 2; ++b2) {
      kb[b2] += __shfl_xor(kb[b2], 16);
      kb[b2] += __shfl_xor(kb[b2], 32);
    }
    const int hg = 4 * j + hloc;
    if (kq == 0 && q == 0) {
#pragma unroll
      for (int b2 = 0; b2 < 2; ++b2) {
        int bb = 8 * s + 2 * bq + b2;
        st_coh4(&kw[bb * 128 + hg], kb[b2]);
        float& ka = (b2 == 0) ? ka0 : ka1;
        if (e == 0) ka = kb[b2];
        else ka = fmaf((e == 3) ? 1.f : 2.f, kb[b2], ka);
        if (e == 3) {
          float dt = s_dt[bb];
          float yn = ld_coh4(&yw[cur * 2048 + bb * 128 + hg]) + dt * (1.f / 6.f) * ka;
          st_coh4(&yw[nxt * 2048 + bb * 128 + hg], yn);
          int b = g * 16 + bb;
          out[(size_t)b * 8192 + (size_t)(l + 1) * 128 + hg] =
              (s_ts[bb][l + 1] <= s_tm[bb]) ? yn : -99.f;
        }
      }
    }
  };

  // ---------------- init MLP: y0 = MLP_i(x0), weights from global ----------
  {
    int bb = tid >> 4, d = tid & 15;
    float t0 = s_ts[bb][0];
    int sj = seg_idx(&s_kn[bb][0], t0);
    float k0 = s_kn[bb][sj], k1 = s_kn[bb][sj + 1];
    float fr = (t0 - k0) / (k1 - k0);
    const float* ob = obs + ((size_t)(g * 16 + bb) * 64 + sj) * 16 + d;
    float o0 = ob[0], o1 = ob[16];
    s_y[bb][d] = fmaf(fr, o1 - o0, o0);
  }
  __syncthreads();
  if (tid < 128) {  // L1i: 16-in, 8-row slice
    int bb = tid & 15, o = tid >> 4;
    float acc = i_bin[8 * j + o];
    const float* wr = i_win + (size_t)(8 * j + o) * 16;
#pragma unroll
    for (int i2 = 0; i2 < 16; ++i2) acc = fmaf(wr[i2], s_y[bb][i2], acc);
    st_coh4(&h1[bb * 256 + 8 * j + o], sp(acc));
  }
  ++epA; signal(flagA, epA); wait(flagA, epA);
  for (int layer = 0; layer < 2; ++layer) {  // mid-i layers, global weights
    stageH(0, layer == 0 ? h1 : h2);
    stageH(1, layer == 0 ? h1 : h2);
    int bb = tid & 15, kh = (tid >> 4) & 1, o = tid >> 5;
    float acc = 0.f;
    const float* wr = i_wmid + (size_t)layer * 65536 + (size_t)(8 * j + o) * 256 + kh * 128;
    const float* ar = &s_act[bb][kh * 136];
#pragma unroll
    for (int c = 0; c < 32; ++c) {
      float4 wv = *(const float4*)(wr + 4 * c);
      int off = 4 * c + 4 * (c >> 4);
      acc = dot4(wv, *(const float4*)(ar + off), acc);
    }
    acc += __shfl_xor(acc, 16);
    if (kh == 0) {
      float* hdst = (layer == 0 ? h2 : h3);
      st_coh4(&hdst[bb * 256 + 8 * j + o], sp(acc + i_bmid[layer * 256 + 8 * j + o]));
    }
    ++epA; signal(flagA, epA); wait(flagA, epA);
  }
  {  // L4i: 4-row slice of 128-wide y0, identity; commit y0 + out row 0
    stageH(0, h3);
    stageH(1, h3);
    int bb = tid & 15, kq4 = (tid >> 4) & 3, rl = tid >> 6;
    float acc = 0.f;
    const float* wr = i_wout + (size_t)(4 * j + rl) * 256 + kq4 * 64;
    const float* ar = &s_act[bb][kq4 * 68];
#pragma unroll
    for (int c = 0; c < 16; ++c)
      acc = dot4(*(const float4*)(wr + 4 * c), *(const float4*)(ar + 4 * c), acc);
    acc += __shfl_xor(acc, 16);
    acc += __shfl_xor(acc, 32);
    if (kq4 == 0) {
      int hg = 4 * j + rl;
      float y0 = acc + i_bout[hg];
      st_coh4(&yw[bb * 128 + hg], y0);
      int b = g * 16 + bb;
      out[(size_t)b * 8192 + hg] = (s_ts[bb][0] <= s_tm[bb]) ? y0 : -99.f;
    }
  }
  ++epA; signal(flagA, epA);

  // ---------------- RK4 over 63 intervals, two-set pipeline ----------------
  float kaA0 = 0.f, kaA1 = 0.f, kaB0 = 0.f, kaB1 = 0.f;

#pragma unroll 1
  for (int l = 0; l < 63; ++l) {
    const int cur = l & 1, nxt = cur ^ 1;
    if (tid < 16) s_dt[tid] = s_ts[tid][l + 1] - s_ts[tid][l];
#pragma unroll 1
    for (int e = 0; e < 4; ++e) {
      // ---- A front: wait prev A4 (covered by prev B.L4), stage y, L1 ----
      wait(flagA, epA);
      {  // prologue: dx(t_e) for all 16 batches (block-local)
        int bb = tid >> 4, d = tid & 15;
        float t0 = s_ts[bb][l], t1 = s_ts[bb][l + 1];
        float te = (e == 0) ? t0 : ((e == 3) ? t1 : fmaf(0.5f, t1 - t0, t0));
        int sj = seg_idx(&s_kn[bb][0], te);
        const float* ob = obs + ((size_t)(g * 16 + bb) * 64 + sj) * 16 + d;
        s_dx[bb][d] = (ob[16] - ob[0]) / (s_kn[bb][sj + 1] - s_kn[bb][sj]);
      }
      stageY(0, cur, e);
      __syncthreads();
      L1f(0);
      ++epA; signal(flagA, epA);       // A1

      wait(flagB, epB);                // prev B4 (covered by A front)
      stageY(1, cur, e);
      __syncthreads();
      L1f(1);
      ++epB; signal(flagB, epB);       // B1

      wait(flagA, epA);                // A1 (covered by B front)
      stageH(0, h1); midf(0, w_m0, sb_m0, h2);
      ++epA; signal(flagA, epA);       // A2

      wait(flagB, epB);                // B1 (covered by A.m0)
      stageH(1, h1); midf(1, w_m0, sb_m0, h2);
      ++epB; signal(flagB, epB);       // B2

      wait(flagA, epA);                // A2 (covered by B.m0)
      stageH(0, h2); midf(0, w_m1, sb_m1, h3);
      ++epA; signal(flagA, epA);       // A3

      wait(flagB, epB);                // B2 (covered by A.m1)
      stageH(1, h2); midf(1, w_m1, sb_m1, h3);
      ++epB; signal(flagB, epB);       // B3

      wait(flagA, epA);                // A3 (covered by B.m1)
      stageH(0, h3); L4f(0, e, cur, nxt, l, kaA0, kaA1);
      ++epA; signal(flagA, epA);       // A4

      wait(flagB, epB);                // B3 (covered by A.L4)
      stageH(1, h3); L4f(1, e, cur, nxt, l, kaB0, kaB1);
      ++epB; signal(flagB, epB);       // B4
    }
  }
}

extern "C" void kernel_launch(void* const* d_in, const int* in_sizes, int n_in,
                              void* d_out, int out_size, void* d_ws, size_t ws_size,
                              hipStream_t stream) {
  const float* ts     = (const float*)d_in[0];
  const float* tsi    = (const float*)d_in[1];
  const float* obs    = (const float*)d_in[2];
  const float* tmaxp  = (const float*)d_in[3];
  const float* i_win  = (const float*)d_in[4];
  const float* i_bin  = (const float*)d_in[5];
  const float* i_wmid = (const float*)d_in[6];
  const float* i_bmid = (const float*)d_in[7];
  const float* i_wout = (const float*)d_in[8];
  const float* i_bout = (const float*)d_in[9];
  const float* v_win  = (const float*)d_in[10];
  const float* v_bin  = (const float*)d_in[11];
  const float* v_wmid = (const float*)d_in[12];
  const float* v_bmid = (const float*)d_in[13];
  const float* v_wout = (const float*)d_in[14];
  const float* v_bout = (const float*)d_in[15];

  // zero the epoch flags (first 4KB of ws) each launch (graph-capture safe)
  (void)hipMemsetAsync(d_ws, 0, 4096, stream);

  ncde_kernel<<<dim3(NGRP * NJ), dim3(NTHR), 0, stream>>>(
      ts, tsi, obs, tmaxp,
      i_win, i_bin, i_wmid, i_bmid, i_wout, i_bout,
      v_win, v_bin, v_wmid, v_bmid, v_wout, v_bout,
      (float*)d_out, (uint32_t*)d_ws);
}

// Round 5
// 5117.256 us; speedup vs baseline: 2.3355x; 1.1964x over previous
//
#include <hip/hip_runtime.h>
#include <stdint.h>

// Online Neural CDE, fused persistent kernel — fp32 datapath, two-set pipeline,
// 512-thread blocks (2 waves/SIMD for latency hiding).
// 8 groups x 32 blocks; group = 16 batches, split into sets A(0-7)/B(8-15).
// Each block holds a 1/32 output-row-slice of the vector-field weights in LDS.
// Cross-block exchange via fine-grained agent-scope (sc1) loads/stores through
// the Infinity Cache; group sync via per-block epoch flags.

#define NGRP 8
#define NJ   32
#define NTHR 512
#define STW  276   // dword stride for 256-col tiles (4-dword gap per 64 cols)
#define STY  132   // dword stride for 128-col y tile (gap at col 64)

typedef unsigned long long u64t;

static __device__ __forceinline__ u64t ld_coh8(const u64t* p) {
  return __hip_atomic_load(p, __ATOMIC_RELAXED, __HIP_MEMORY_SCOPE_AGENT);
}
static __device__ __forceinline__ float ld_coh4(const float* p) {
  return __hip_atomic_load(p, __ATOMIC_RELAXED, __HIP_MEMORY_SCOPE_AGENT);
}
static __device__ __forceinline__ void st_coh4(float* p, float v) {
  __hip_atomic_store(p, v, __ATOMIC_RELAXED, __HIP_MEMORY_SCOPE_AGENT);
}

// jax.nn.softplus(x) = max(x,0) + log1p(exp(-|x|))
static __device__ __forceinline__ float sp(float x) {
  return fmaxf(x, 0.f) + log1pf(expf(-fabsf(x)));
}

// np.searchsorted(kn, t, 'right') - 1, clipped to [0, 62]; 64 knots.
static __device__ __forceinline__ int seg_idx(const float* kn, float t) {
  int lo = 0, hi = 64;
  while (lo < hi) { int mid = (lo + hi) >> 1; if (kn[mid] <= t) lo = mid + 1; else hi = mid; }
  int jj = lo - 1;
  return jj < 0 ? 0 : (jj > 62 ? 62 : jj);
}

static __device__ __forceinline__ float dot4(float4 w, float4 a, float acc) {
  acc = fmaf(w.x, a.x, acc);
  acc = fmaf(w.y, a.y, acc);
  acc = fmaf(w.z, a.z, acc);
  return fmaf(w.w, a.w, acc);
}

__global__ void __launch_bounds__(NTHR)
ncde_kernel(const float* __restrict__ ts, const float* __restrict__ tsi,
            const float* __restrict__ obs, const float* __restrict__ tmax,
            const float* __restrict__ i_win, const float* __restrict__ i_bin,
            const float* __restrict__ i_wmid, const float* __restrict__ i_bmid,
            const float* __restrict__ i_wout, const float* __restrict__ i_bout,
            const float* __restrict__ v_win, const float* __restrict__ v_bin,
            const float* __restrict__ v_wmid, const float* __restrict__ v_bmid,
            const float* __restrict__ v_wout, const float* __restrict__ v_bout,
            float* __restrict__ out, uint32_t* __restrict__ ws)
{
  __shared__ __align__(16) float w_l4[64][STW];   // v_wout rows 64j..64j+63
  __shared__ __align__(16) float w_m0[8][STW];    // v_wmid[0] rows 8j..
  __shared__ __align__(16) float w_m1[8][STW];    // v_wmid[1] rows 8j..
  __shared__ __align__(16) float w_l1[8][STY];    // v_win rows 8j..
  __shared__ __align__(16) float s_act[16][STW];  // staged activations (rows 8s..)
  __shared__ __align__(16) float s_y[16][STY];    // staged y input (rows 8s..)
  __shared__ __align__(16) float s_ts[16][64];
  __shared__ __align__(16) float s_kn[16][64];
  __shared__ float s_dx[16][16];
  __shared__ float s_dt[16], s_tm[16];
  __shared__ float sb_l1[8], sb_m0[8], sb_m1[8], sb_l4[64];

  const int tid = threadIdx.x;
  const int bid = blockIdx.x;
  const int g = bid & 7;    // group (== XCD under round-robin; perf heuristic only)
  const int j = bid >> 3;   // slice 0..31

  uint32_t* flagA = ws + (size_t)(g * 2 + 0) * 64;
  uint32_t* flagB = ws + (size_t)(g * 2 + 1) * 64;
  float* base = (float*)(ws + 1024) + (size_t)g * 18432;
  float* yw = base;           // [2][16][128]
  float* kw = base + 4096;    // [16][128]
  float* h1 = base + 6144;    // [16][256]
  float* h2 = base + 10240;
  float* h3 = base + 14336;

  // ---------------- load weight slices -> LDS (fp32, gapped cols) ----------
  for (int e2 = tid; e2 < 64 * 64; e2 += NTHR) {   // w_l4: 64 rows x 64 f4
    int r = e2 >> 6, c4 = e2 & 63; int k = 4 * c4;
    float4 v = *(const float4*)(v_wout + (size_t)(64 * j + r) * 256 + k);
    *(float4*)&w_l4[r][k + 4 * (k >> 6)] = v;
  }
  for (int e2 = tid; e2 < 8 * 64; e2 += NTHR) {    // mids: 8 rows x 64 f4 each
    int r = e2 >> 6, c4 = e2 & 63; int k = 4 * c4;
    float4 a = *(const float4*)(v_wmid + (size_t)(8 * j + r) * 256 + k);
    float4 b2 = *(const float4*)(v_wmid + 65536 + (size_t)(8 * j + r) * 256 + k);
    int col = k + 4 * (k >> 6);
    *(float4*)&w_m0[r][col] = a;
    *(float4*)&w_m1[r][col] = b2;
  }
  if (tid < 256) {                                 // w_l1: 8 rows x 32 f4
    int r = tid >> 5, c4 = tid & 31; int k = 4 * c4;
    float4 v = *(const float4*)(v_win + (size_t)(8 * j + r) * 128 + k);
    *(float4*)&w_l1[r][k + 4 * (k >> 6)] = v;
  }
  if (tid < 8) {
    sb_l1[tid] = v_bin[8 * j + tid];
    sb_m0[tid] = v_bmid[8 * j + tid];
    sb_m1[tid] = v_bmid[256 + 8 * j + tid];
  }
  if (tid < 64) sb_l4[tid] = v_bout[64 * j + tid];
  for (int e2 = tid; e2 < 16 * 64; e2 += NTHR) {
    int bb = e2 >> 6, i2 = e2 & 63;
    int b = g * 16 + bb;
    s_ts[bb][i2] = ts[b * 64 + i2];
    s_kn[bb][i2] = tsi[b * 64 + i2];
  }
  if (tid < 16) s_tm[tid] = tmax[g * 16 + tid];
  __syncthreads();

  uint32_t epA = 0, epB = 0;

  auto signal = [&](uint32_t* flg, uint32_t ep) {
    asm volatile("s_waitcnt vmcnt(0)" ::: "memory");
    __syncthreads();
    if (tid == 0)
      __hip_atomic_store(flg + j, ep, __ATOMIC_RELAXED, __HIP_MEMORY_SCOPE_AGENT);
  };
  auto wait = [&](uint32_t* flg, uint32_t ep) {
    if (tid < 64) {
      uint32_t it = 0;
      for (;;) {
        uint32_t f = __hip_atomic_load(flg + (tid & 31), __ATOMIC_RELAXED,
                                       __HIP_MEMORY_SCOPE_AGENT);
        if (__all((int)(f >= ep))) break;
        __builtin_amdgcn_s_sleep(1);
        if (++it > (1u << 20)) break;  // failsafe: no hang
      }
    }
    __syncthreads();
  };

  // stage 8 batches x 256 acts (sc1) -> gapped LDS rows 8s..8s+7
  auto stageH = [&](int s, const float* hsrc) {
    const u64t* hp = (const u64t*)(hsrc + s * 2048);
#pragma unroll
    for (int it = 0; it < 2; ++it) {
      int e2 = tid + it * NTHR;
      int bb = e2 >> 7, c2 = e2 & 127;
      u64t v = ld_coh8(hp + bb * 128 + c2);
      int k = 2 * c2;
      *(u64t*)&s_act[8 * s + bb][k + 4 * (k >> 6)] = v;
    }
    __syncthreads();
  };

  // L1: 128-in (s_y) -> 8-row slice, softplus. lanes: bb8(0-2) kq8(3-5) o8(wave)
  auto L1f = [&](int s) {
    int bb = tid & 7, kq = (tid >> 3) & 7, o = tid >> 6;
    int off = 16 * kq + 4 * (kq >> 2);
    float acc = 0.f;
    const float* wr = &w_l1[o][off];
    const float* ar = &s_y[8 * s + bb][off];
#pragma unroll
    for (int c = 0; c < 4; ++c)
      acc = dot4(*(const float4*)(wr + 4 * c), *(const float4*)(ar + 4 * c), acc);
    acc += __shfl_xor(acc, 8);
    acc += __shfl_xor(acc, 16);
    acc += __shfl_xor(acc, 32);
    if (kq == 0) st_coh4(&h1[s * 2048 + bb * 256 + 8 * j + o], sp(acc + sb_l1[o]));
  };

  // mid: 256-in (s_act) -> 8-row slice, softplus. lanes: bb8 kq8 o8(wave)
  auto midf = [&](int s, const float (*W)[STW], const float* bias, float* hdst) {
    int bb = tid & 7, kq = (tid >> 3) & 7, o = tid >> 6;
    int off = 32 * kq + 4 * (kq >> 1);
    float acc = 0.f;
    const float* wr = &W[o][off];
    const float* ar = &s_act[8 * s + bb][off];
#pragma unroll
    for (int c = 0; c < 8; ++c)
      acc = dot4(*(const float4*)(wr + 4 * c), *(const float4*)(ar + 4 * c), acc);
    acc += __shfl_xor(acc, 8);
    acc += __shfl_xor(acc, 16);
    acc += __shfl_xor(acc, 32);
    if (kq == 0) st_coh4(&hdst[s * 2048 + bb * 256 + 8 * j + o], sp(acc + bias[o]));
  };

  // stage y_in = y (+ c*dt*k) for one set (8 batches x 128 = 512 u64 loads)
  auto stageY = [&](int s, int cur, int e) {
    const u64t* ywc = (const u64t*)(yw + cur * 2048 + s * 1024);
    const u64t* kwp = (const u64t*)(kw + s * 1024);
    int bb = tid >> 6, c2 = tid & 63;
    float2 yv = __builtin_bit_cast(float2, ld_coh8(ywc + bb * 64 + c2));
    if (e > 0) {
      float cd = ((e == 3) ? 1.f : 0.5f) * s_dt[8 * s + bb];
      float2 kv = __builtin_bit_cast(float2, ld_coh8(kwp + bb * 64 + c2));
      yv.x = fmaf(cd, kv.x, yv.x);
      yv.y = fmaf(cd, kv.y, yv.y);
    }
    int i2 = 2 * c2;
    *(float2*)&s_y[8 * s + bb][i2 + 4 * (i2 >> 6)] = yv;
  };

  // L4: 64-row slice; lanes: kq8(0-2) q4(3-4) bq-lo(5); waves: bq-hi, hloc4.
  auto L4f = [&](int s, int e, int cur, int nxt, int l,
                 float& ka0, float& ka1) {
    const int kq = tid & 7, q = (tid >> 3) & 3, bq = (tid >> 5) & 3, hloc = tid >> 7;
    const int off = 32 * kq + 4 * (kq >> 1);
    const float* wr0 = &w_l4[hloc * 16 + 4 * q][off];
    const float* ar0 = &s_act[8 * s + 2 * bq][off];
    float acc[4][2] = {};
#pragma unroll
    for (int c = 0; c < 8; ++c) {
      float4 wv[4], av[2];
#pragma unroll
      for (int i2 = 0; i2 < 4; ++i2) wv[i2] = *(const float4*)(wr0 + i2 * STW + 4 * c);
#pragma unroll
      for (int b2 = 0; b2 < 2; ++b2) av[b2] = *(const float4*)(ar0 + b2 * STW + 4 * c);
#pragma unroll
      for (int i2 = 0; i2 < 4; ++i2)
#pragma unroll
        for (int b2 = 0; b2 < 2; ++b2)
          acc[i2][b2] = dot4(wv[i2], av[b2], acc[i2][b2]);
    }
#pragma unroll
    for (int i2 = 0; i2 < 4; ++i2)
#pragma unroll
      for (int b2 = 0; b2 < 2; ++b2) {   // butterfly over kq: all lanes get sum
        acc[i2][b2] += __shfl_xor(acc[i2][b2], 1);
        acc[i2][b2] += __shfl_xor(acc[i2][b2], 2);
        acc[i2][b2] += __shfl_xor(acc[i2][b2], 4);
      }
    float kb[2];
#pragma unroll
    for (int b2 = 0; b2 < 2; ++b2) {
      float sacc = 0.f;
      int bb = 8 * s + 2 * bq + b2;
#pragma unroll
      for (int i2 = 0; i2 < 4; ++i2) {
        float z = acc[i2][b2] + sb_l4[hloc * 16 + 4 * q + i2];
        sacc = fmaf(tanhf(z), s_dx[bb][4 * q + i2], sacc);
      }
      kb[b2] = sacc;
    }
#pragma unroll
    for (int b2 = 0; b2 < 2; ++b2) {     // butterfly over q
      kb[b2] += __shfl_xor(kb[b2], 8);
      kb[b2] += __shfl_xor(kb[b2], 16);
    }
    // all lanes hold full kb; maintain ka uniformly, writers store
    if (e == 0) { ka0 = kb[0]; ka1 = kb[1]; }
    else {
      float wk = (e == 3) ? 1.f : 2.f;
      ka0 = fmaf(wk, kb[0], ka0);
      ka1 = fmaf(wk, kb[1], ka1);
    }
    const int hg = 4 * j + hloc;
    if (kq == 0 && q == 0) {
#pragma unroll
      for (int b2 = 0; b2 < 2; ++b2) {
        int bb = 8 * s + 2 * bq + b2;
        st_coh4(&kw[bb * 128 + hg], kb[b2]);
        if (e == 3) {
          float ka = (b2 == 0) ? ka0 : ka1;
          float dt = s_dt[bb];
          float yn = ld_coh4(&yw[cur * 2048 + bb * 128 + hg]) + dt * (1.f / 6.f) * ka;
          st_coh4(&yw[nxt * 2048 + bb * 128 + hg], yn);
          int b = g * 16 + bb;
          out[(size_t)b * 8192 + (size_t)(l + 1) * 128 + hg] =
              (s_ts[bb][l + 1] <= s_tm[bb]) ? yn : -99.f;
        }
      }
    }
  };

  // ---------------- init MLP: y0 = MLP_i(x0), weights from global ----------
  if (tid < 256) {
    int bb = tid >> 4, d = tid & 15;
    float t0 = s_ts[bb][0];
    int sj = seg_idx(&s_kn[bb][0], t0);
    float k0 = s_kn[bb][sj], k1 = s_kn[bb][sj + 1];
    float fr = (t0 - k0) / (k1 - k0);
    const float* ob = obs + ((size_t)(g * 16 + bb) * 64 + sj) * 16 + d;
    float o0 = ob[0], o1 = ob[16];
    s_y[bb][d] = fmaf(fr, o1 - o0, o0);
  }
  __syncthreads();
  if (tid < 128) {  // L1i: 16-in, 8-row slice
    int bb = tid & 15, o = tid >> 4;
    float acc = i_bin[8 * j + o];
    const float* wr = i_win + (size_t)(8 * j + o) * 16;
#pragma unroll
    for (int i2 = 0; i2 < 16; ++i2) acc = fmaf(wr[i2], s_y[bb][i2], acc);
    st_coh4(&h1[bb * 256 + 8 * j + o], sp(acc));
  }
  ++epA; signal(flagA, epA); wait(flagA, epA);
  for (int layer = 0; layer < 2; ++layer) {  // mid-i: bb16 kq4 o8 (512 thr)
    stageH(0, layer == 0 ? h1 : h2);
    stageH(1, layer == 0 ? h1 : h2);
    int bb = tid & 15, kq = (tid >> 4) & 3, o = tid >> 6;
    float acc = 0.f;
    const float* wr = i_wmid + (size_t)layer * 65536 + (size_t)(8 * j + o) * 256 + kq * 64;
    const float* ar = &s_act[bb][68 * kq];
#pragma unroll
    for (int c = 0; c < 16; ++c)
      acc = dot4(*(const float4*)(wr + 4 * c), *(const float4*)(ar + 4 * c), acc);
    acc += __shfl_xor(acc, 16);
    acc += __shfl_xor(acc, 32);
    if (kq == 0) {
      float* hdst = (layer == 0 ? h2 : h3);
      st_coh4(&hdst[bb * 256 + 8 * j + o], sp(acc + i_bmid[layer * 256 + 8 * j + o]));
    }
    ++epA; signal(flagA, epA); wait(flagA, epA);
  }
  {  // L4i: 4-row slice of 128-wide y0, identity; commit y0 + out row 0
    stageH(0, h3);
    stageH(1, h3);
    if (tid < 256) {
      int bb = tid & 15, kq4 = (tid >> 4) & 3, rl = tid >> 6;
      float acc = 0.f;
      const float* wr = i_wout + (size_t)(4 * j + rl) * 256 + kq4 * 64;
      const float* ar = &s_act[bb][kq4 * 68];
#pragma unroll
      for (int c = 0; c < 16; ++c)
        acc = dot4(*(const float4*)(wr + 4 * c), *(const float4*)(ar + 4 * c), acc);
      acc += __shfl_xor(acc, 16);
      acc += __shfl_xor(acc, 32);
      if (kq4 == 0) {
        int hg = 4 * j + rl;
        float y0 = acc + i_bout[hg];
        st_coh4(&yw[bb * 128 + hg], y0);
        int b = g * 16 + bb;
        out[(size_t)b * 8192 + hg] = (s_ts[bb][0] <= s_tm[bb]) ? y0 : -99.f;
      }
    }
  }
  ++epA; signal(flagA, epA);

  // ---------------- RK4 over 63 intervals, two-set pipeline ----------------
  float kaA0 = 0.f, kaA1 = 0.f, kaB0 = 0.f, kaB1 = 0.f;

#pragma unroll 1
  for (int l = 0; l < 63; ++l) {
    const int cur = l & 1, nxt = cur ^ 1;
    if (tid < 16) s_dt[tid] = s_ts[tid][l + 1] - s_ts[tid][l];
#pragma unroll 1
    for (int e = 0; e < 4; ++e) {
      wait(flagA, epA);                        // prev A4
      if (tid < 256) {  // prologue: dx(t_e) for all 16 batches
        int bb = tid >> 4, d = tid & 15;
        float t0 = s_ts[bb][l], t1 = s_ts[bb][l + 1];
        float te = (e == 0) ? t0 : ((e == 3) ? t1 : fmaf(0.5f, t1 - t0, t0));
        int sj = seg_idx(&s_kn[bb][0], te);
        const float* ob = obs + ((size_t)(g * 16 + bb) * 64 + sj) * 16 + d;
        s_dx[bb][d] = (ob[16] - ob[0]) / (s_kn[bb][sj + 1] - s_kn[bb][sj]);
      }
      stageY(0, cur, e);
      __syncthreads();
      L1f(0);
      ++epA; signal(flagA, epA);               // A1

      wait(flagB, epB);                        // prev B4
      stageY(1, cur, e);
      __syncthreads();
      L1f(1);
      ++epB; signal(flagB, epB);               // B1

      wait(flagA, epA);                        // A1
      stageH(0, h1); midf(0, w_m0, sb_m0, h2);
      ++epA; signal(flagA, epA);               // A2

      wait(flagB, epB);                        // B1
      stageH(1, h1); midf(1, w_m0, sb_m0, h2);
      ++epB; signal(flagB, epB);               // B2

      wait(flagA, epA);                        // A2
      stageH(0, h2); midf(0, w_m1, sb_m1, h3);
      ++epA; signal(flagA, epA);               // A3

      wait(flagB, epB);                        // B2
      stageH(1, h2); midf(1, w_m1, sb_m1, h3);
      ++epB; signal(flagB, epB);               // B3

      wait(flagA, epA);                        // A3
      stageH(0, h3); L4f(0, e, cur, nxt, l, kaA0, kaA1);
      ++epA; signal(flagA, epA);               // A4

      wait(flagB, epB);                        // B3
      stageH(1, h3); L4f(1, e, cur, nxt, l, kaB0, kaB1);
      ++epB; signal(flagB, epB);               // B4
    }
  }
}

extern "C" void kernel_launch(void* const* d_in, const int* in_sizes, int n_in,
                              void* d_out, int out_size, void* d_ws, size_t ws_size,
                              hipStream_t stream) {
  const float* ts     = (const float*)d_in[0];
  const float* tsi    = (const float*)d_in[1];
  const float* obs    = (const float*)d_in[2];
  const float* tmaxp  = (const float*)d_in[3];
  const float* i_win  = (const float*)d_in[4];
  const float* i_bin  = (const float*)d_in[5];
  const float* i_wmid = (const float*)d_in[6];
  const float* i_bmid = (const float*)d_in[7];
  const float* i_wout = (const float*)d_in[8];
  const float* i_bout = (const float*)d_in[9];
  const float* v_win  = (const float*)d_in[10];
  const float* v_bin  = (const float*)d_in[11];
  const float* v_wmid = (const float*)d_in[12];
  const float* v_bmid = (const float*)d_in[13];
  const float* v_wout = (const float*)d_in[14];
  const float* v_bout = (const float*)d_in[15];

  // zero the epoch flags (first 4KB of ws) each launch (graph-capture safe)
  (void)hipMemsetAsync(d_ws, 0, 4096, stream);

  ncde_kernel<<<dim3(NGRP * NJ), dim3(NTHR), 0, stream>>>(
      ts, tsi, obs, tmaxp,
      i_win, i_bin, i_wmid, i_bmid, i_wout, i_bout,
      v_win, v_bin, v_wmid, v_bmid, v_wout, v_bout,
      (float*)d_out, (uint32_t*)d_ws);
}